// Round 18
// baseline (132.038 us; speedup 1.0000x reference)
//
#include <hip/hip_runtime.h>

#define NVEC 65536   // B*H*W = 64*32*32
#define KCB  1024
#define DIM  128
#define HW   1024    // H*W
#define CHUNK 32
#define NCHUNKS (NVEC / CHUNK)

typedef __bf16 b16;
typedef b16 b16x8 __attribute__((ext_vector_type(8)));
typedef float f32x16 __attribute__((ext_vector_type(16)));

static __device__ __forceinline__ unsigned short f2bf(float f) {
  unsigned int x = __float_as_uint(f);
  unsigned int r = x + 0x7fffu + ((x >> 16) & 1u);   // RNE
  return (unsigned short)(r >> 16);
}

// ---- fused prep: cbt pack + out6=0.99*emw + hist=0 + ccb(f32) + cc64(f64) -
__global__ void k_prep(const float* __restrict__ cb, const float* __restrict__ emw,
                       uint4* __restrict__ cbt, float* __restrict__ ccb,
                       double* __restrict__ cc64, float* __restrict__ out6,
                       int* __restrict__ hist) {
  const int t = blockIdx.x * blockDim.x + threadIdx.x;   // 16384
  const int kc = t >> 11, u = t & 2047;
  const int code7 = u & 127, dch = u >> 7;
  const float* src = cb + (kc * 128 + code7) * 128 + dch * 8;
  const float4 x = *(const float4*)src;
  const float4 y = *(const float4*)(src + 4);
  uint4 o;
  o.x = (unsigned)f2bf(x.x) | ((unsigned)f2bf(x.y) << 16);
  o.y = (unsigned)f2bf(x.z) | ((unsigned)f2bf(x.w) << 16);
  o.z = (unsigned)f2bf(y.x) | ((unsigned)f2bf(y.y) << 16);
  o.w = (unsigned)f2bf(y.z) | ((unsigned)f2bf(y.w) << 16);
  cbt[t] = o;
  // out6 init: out6 offset is 8B- but not 16B-aligned -> float2 stores
  const float4 e0 = *(const float4*)(emw + (size_t)t * 8);
  const float4 e1 = *(const float4*)(emw + (size_t)t * 8 + 4);
  *(float2*)(out6 + (size_t)t * 8 + 0) = make_float2(0.99f * e0.x, 0.99f * e0.y);
  *(float2*)(out6 + (size_t)t * 8 + 2) = make_float2(0.99f * e0.z, 0.99f * e0.w);
  *(float2*)(out6 + (size_t)t * 8 + 4) = make_float2(0.99f * e1.x, 0.99f * e1.y);
  *(float2*)(out6 + (size_t)t * 8 + 6) = make_float2(0.99f * e1.z, 0.99f * e1.w);
  if (t < KCB) hist[t] = 0;
  if (blockIdx.x < 4) {
    const int k = blockIdx.x * 256 + threadIdx.x;
    const float* row = cb + k * DIM;
    double s = 0.0;
#pragma unroll 8
    for (int j = 0; j < DIM; ++j) {
      const double v = (double)row[j];
      s = fma(v, v, s);
    }
    cc64[k] = s;
    ccb[k] = 512.f - 0.5f * (float)s;   // bias keeps packed scores positive
  }
}

// ---- MFMA argmin: single-barrier double-buffered pipeline (T3 minimal) ----
// 16 chunks x 64 codes; per chunk: barrier (drains stage(c); readers of nxt
// done) -> issue stage(c+1 -> nxt) -> compute(c, cur). The load lands under
// compute(c) so the next barrier's vmcnt(0) drain is free (R8's structure
// stalled the full L2 latency per chunk: issue -> drain -> compute).
// Spill-proof: pointer-ternary buffer select, scalar ccb loads, one f32x16
// acc (R11's ccv[16] and R10/R12's register tiles all spilled -- rule #20).
// Wave wv: rows wr=(wv&1)*32, code column cg=wv>>1 (32 codes of each chunk).
// Per-wave top-2 covers an interleaved 512-code subset; 2 subsets x top-2 =
// same 4-candidate envelope as before; f64 rescore unchanged.
__global__ __launch_bounds__(256, 4) void k_argmin7(
    const float* __restrict__ z, const uint4* __restrict__ cbt,
    const float* __restrict__ ccb, const double* __restrict__ cc64,
    const float* __restrict__ cb, float* __restrict__ z_t,
    float* __restrict__ out1, int* __restrict__ hist) {
  __shared__ __align__(16) float zs[128][65];          // 33.3 KB; Bs0/Bs1/hist alias
  __shared__ uint2 cand[64][2];                        // 1 KB candidate exchange
  uint4* Bs0 = (uint4*)zs;                             // 16 KB
  uint4* Bs1 = ((uint4*)zs) + 1024;                    // 16 KB
  const int tid = threadIdx.x;
  const int l = tid & 63, wv = tid >> 6;
  const int g = l >> 5;                            // k-slice group
  const int lm = l & 31;                           // row-lane / code-lane
  const int wr = (wv & 1) * 32;                    // row group
  const int cg = wv >> 1;                          // code col-group in chunk
  const int n0 = blockIdx.x * 64;
  const int b = n0 >> 10;
  const int hwbase = n0 & (HW - 1);

  // ---- phase 0: coalesced stage of the z tile into LDS
  {
    const int hw4 = (tid & 15) * 4;
    const int dr = tid >> 4;
    const float* src = z + (size_t)b * 131072 + hwbase + hw4;
#pragma unroll
    for (int j = 0; j < 8; ++j) {
      const int d = dr + 16 * j;
      const float4 v = *(const float4*)(src + d * 1024);
      zs[d][hw4 + 0] = v.x; zs[d][hw4 + 1] = v.y;
      zs[d][hw4 + 2] = v.z; zs[d][hw4 + 3] = v.w;
    }
  }
  __syncthreads();

  // ---- phase 1a: z_t rows, full-line stores (8 lanes x 16B per 512B row)
#pragma unroll
  for (int jj = 0; jj < 2; ++jj) {
    const int row = (tid >> 3) + 32 * jj;
    float* dst = z_t + ((size_t)(n0 + row)) * 128;
#pragma unroll
    for (int j = 0; j < 4; ++j) {
      const int d = (j * 8 + (tid & 7)) * 4;
      float4 v;
      v.x = zs[d + 0][row]; v.y = zs[d + 1][row];
      v.z = zs[d + 2][row]; v.w = zs[d + 3][row];
      *(float4*)(dst + d) = v;
    }
  }
  // ---- phase 1b: afrag from LDS
  uint4 afrag[8];
  {
    const int row = wr + lm;
#pragma unroll
    for (int ks = 0; ks < 8; ++ks) {
      const int d0 = ks * 16 + g * 8;
      afrag[ks].x = (unsigned)f2bf(zs[d0 + 0][row]) | ((unsigned)f2bf(zs[d0 + 1][row]) << 16);
      afrag[ks].y = (unsigned)f2bf(zs[d0 + 2][row]) | ((unsigned)f2bf(zs[d0 + 3][row]) << 16);
      afrag[ks].z = (unsigned)f2bf(zs[d0 + 4][row]) | ((unsigned)f2bf(zs[d0 + 5][row]) << 16);
      afrag[ks].w = (unsigned)f2bf(zs[d0 + 6][row]) | ((unsigned)f2bf(zs[d0 + 7][row]) << 16);
    }
  }

  unsigned pm1[16], pm2[16];
#pragma unroll
  for (int r = 0; r < 16; ++r) { pm1[r] = 0u; pm2[r] = 0u; }

  __syncthreads();                     // zs readers done; Bs may overwrite
  // prologue: stage chunk 0 (kc=0, half=0) into Bs0
#pragma unroll
  for (int i = 0; i < 4; ++i) {
    const int dch = wv * 4 + i;
    __builtin_amdgcn_global_load_lds(&cbt[dch * 128 + l], &Bs0[dch * 64], 16, 0, 0);
  }

  for (int c = 0; c < 16; ++c) {
    __syncthreads();                   // drains stage(c); readers of nxt done
    const uint4* cur = (c & 1) ? Bs1 : Bs0;
    uint4* nxt = (c & 1) ? Bs0 : Bs1;
    if (c < 15) {                      // issue stage(c+1): lands under compute
      const int c1 = c + 1, kc = c1 >> 1, h = c1 & 1;
#pragma unroll
      for (int i = 0; i < 4; ++i) {
        const int dch = wv * 4 + i;
        __builtin_amdgcn_global_load_lds(&cbt[kc * 2048 + dch * 128 + h * 64 + l],
                                         &nxt[dch * 64], 16, 0, 0);
      }
    }
    const int cbase = c * 64 + cg * 32 + lm;
    const float cv = ccb[cbase];
    f32x16 acc;
#pragma unroll
    for (int j = 0; j < 16; ++j) acc[j] = cv;
#pragma unroll
    for (int ks = 0; ks < 8; ++ks) {
      const b16x8 av = *reinterpret_cast<const b16x8*>(&afrag[ks]);
      const b16x8 bv = *reinterpret_cast<const b16x8*>(
          &cur[(ks * 2 + g) * 64 + cg * 32 + lm]);
      acc = __builtin_amdgcn_mfma_f32_32x32x16_bf16(av, bv, acc, 0, 0, 0);
    }
    const unsigned ci = 1023u - (unsigned)cbase;
#pragma unroll
    for (int r = 0; r < 16; ++r) {
      const unsigned uu = ((__float_as_uint(acc[r]) + 0x200u) & 0xFFFFFC00u) | ci;
      const unsigned tt = pm1[r] < uu ? pm1[r] : uu;
      pm1[r] = pm1[r] > uu ? pm1[r] : uu;
      pm2[r] = pm2[r] > tt ? pm2[r] : tt;
    }
  }

  // top-2 (max-order) merge across the 32 code-lanes -> cand LDS
#pragma unroll
  for (int r = 0; r < 16; ++r) {
    unsigned u1 = pm1[r], u2 = pm2[r];
#pragma unroll
    for (int m = 1; m < 32; m <<= 1) {
      const unsigned o1 = (unsigned)__shfl_xor((int)u1, m, 64);
      const unsigned o2 = (unsigned)__shfl_xor((int)u2, m, 64);
      const unsigned s = u1 < o1 ? u1 : o1;
      u1 = u1 > o1 ? u1 : o1;
      u2 = u2 > o2 ? u2 : o2;
      u2 = u2 > s ? u2 : s;
    }
    if (lm == 0) {
      const int lrow = wr + (r & 3) + 8 * (r >> 2) + 4 * g;
      cand[lrow][cg] = make_uint2(u1, u2);
    }
  }
  __syncthreads();                   // compute reads of Bs done; cand visible

  // ---- wave-parallel rescore: per row, cand c=l>>4 x 16 lanes (8 dims each)
  int* h = (int*)zs;                 // hist aliases dead Bs region
#pragma unroll
  for (int j = 0; j < 4; ++j) h[tid + 256 * j] = 0;
  __syncthreads();
  {
    const int db = l & 15, c = l >> 4;
#pragma unroll 2
    for (int it = 0; it < 16; ++it) {
      const int row = wv * 16 + it;
      const uint2 cd = cand[row][c >> 1];
      const unsigned u = (c & 1) ? cd.y : cd.x;
      int k = 1023 - (int)(u & 1023u);
      const int n = n0 + row;
      const float4* zr = (const float4*)(z_t + (size_t)n * DIM) + db * 2;
      const float4* cr = (const float4*)(cb + (size_t)k * DIM) + db * 2;
      const float4 z0 = zr[0], z1 = zr[1];
      const float4 c0 = cr[0], c1 = cr[1];
      double da = 0.0, dbb = 0.0;
      da = fma((double)z0.x, (double)c0.x, da);
      da = fma((double)z0.y, (double)c0.y, da);
      da = fma((double)z0.z, (double)c0.z, da);
      da = fma((double)z0.w, (double)c0.w, da);
      dbb = fma((double)z1.x, (double)c1.x, dbb);
      dbb = fma((double)z1.y, (double)c1.y, dbb);
      dbb = fma((double)z1.z, (double)c1.z, dbb);
      dbb = fma((double)z1.w, (double)c1.w, dbb);
      double s = da + dbb;
#pragma unroll
      for (int m = 1; m < 16; m <<= 1) s += __shfl_xor(s, m, 64);
      s = fma(-2.0, s, cc64[k]);
#pragma unroll
      for (int m = 16; m < 64; m <<= 1) {
        const double os = __shfl_xor(s, m, 64);
        const int ok = __shfl_xor(k, m, 64);
        if (os < s || (os == s && ok < k)) { s = os; k = ok; }
      }
      if (l == 0) {
        out1[n] = (float)k;
        atomicAdd(&h[k], 1);
      }
    }
  }
  __syncthreads();
#pragma unroll
  for (int j = 0; j < 4; ++j) {
    const int v = h[tid + 256 * j];
    if (v) atomicAdd(&hist[tid + 256 * j], v);
  }
}

// ---- exclusive scan over 1024 bins + out5 + ntot (single block) -----------
__global__ void k_scan(const int* __restrict__ hist, const float* __restrict__ emc,
                       int* __restrict__ cursor, float* __restrict__ out5,
                       float* __restrict__ ntot) {
  __shared__ int tmp[KCB];
  __shared__ float red[16];
  const int t = threadIdx.x;
  const int v = hist[t];
  tmp[t] = v;
  __syncthreads();
  for (int off = 1; off < KCB; off <<= 1) {
    int x = 0;
    if (t >= off) x = tmp[t - off];
    __syncthreads();
    if (t >= off) tmp[t] += x;
    __syncthreads();
  }
  cursor[t] = tmp[t] - v;
  float o5 = 0.99f * emc[t] + 0.01f * (float)v;
  out5[t] = o5;
#pragma unroll
  for (int m = 32; m; m >>= 1) o5 += __shfl_xor(o5, m, 64);
  if ((t & 63) == 0) red[t >> 6] = o5;
  __syncthreads();
  if (t == 0) {
    float s = 0.f;
#pragma unroll
    for (int j = 0; j < 16; ++j) s += red[j];
    *ntot = s;
  }
}

// ------- scatter n's into per-code segments (packed uint2 {n,k}) -----------
__global__ void k_scatter(const float* __restrict__ idx_f, int* __restrict__ cursor,
                          uint2* __restrict__ ok) {
  const int n = blockIdx.x * blockDim.x + threadIdx.x;
  const int k = (int)idx_f[n];
  const int pos = atomicAdd(&cursor[k], 1);
  ok[pos] = make_uint2((unsigned)n, (unsigned)k);
}

// ---- chunk-parallel segmented reduce + quantized write + loss partial -----
// CHUNK=32 (grid 2048 = 8 blocks/CU): 2x TLP for the latency-bound gather.
__global__ __launch_bounds__(128) void k_chunkreduce_q(
    float* zq, const float* __restrict__ cb, const uint2* __restrict__ ok,
    float* __restrict__ out6, float* __restrict__ lossp) {
  __shared__ int so[CHUNK], sk[CHUNK];
  __shared__ float red[2];
  const int t = threadIdx.x;
  const int base = blockIdx.x * CHUNK;
  if (t < CHUNK) {
    const uint2 v = ok[base + t];
    so[t] = (int)v.x; sk[t] = (int)v.y;
  }
  __syncthreads();
  int kprev = sk[0];
  float cbv = cb[kprev * 128 + t];
  float acc = 0.f, loss = 0.f;
  int i = 0;
  while (i < CHUNK) {
    if (i + 8 <= CHUNK && sk[i] == kprev && sk[i + 7] == kprev) {
      const int n0 = so[i + 0], n1 = so[i + 1], n2 = so[i + 2], n3 = so[i + 3];
      const int n4 = so[i + 4], n5 = so[i + 5], n6 = so[i + 6], n7 = so[i + 7];
      const float v0 = zq[(size_t)n0 * 128 + t];
      const float v1 = zq[(size_t)n1 * 128 + t];
      const float v2 = zq[(size_t)n2 * 128 + t];
      const float v3 = zq[(size_t)n3 * 128 + t];
      const float v4 = zq[(size_t)n4 * 128 + t];
      const float v5 = zq[(size_t)n5 * 128 + t];
      const float v6 = zq[(size_t)n6 * 128 + t];
      const float v7 = zq[(size_t)n7 * 128 + t];
      acc += ((v0 + v1) + (v2 + v3)) + ((v4 + v5) + (v6 + v7));
      float e;
      e = cbv - v0; loss = fmaf(e, e, loss);
      e = cbv - v1; loss = fmaf(e, e, loss);
      e = cbv - v2; loss = fmaf(e, e, loss);
      e = cbv - v3; loss = fmaf(e, e, loss);
      e = cbv - v4; loss = fmaf(e, e, loss);
      e = cbv - v5; loss = fmaf(e, e, loss);
      e = cbv - v6; loss = fmaf(e, e, loss);
      e = cbv - v7; loss = fmaf(e, e, loss);
      zq[(size_t)n0 * 128 + t] = cbv; zq[(size_t)n1 * 128 + t] = cbv;
      zq[(size_t)n2 * 128 + t] = cbv; zq[(size_t)n3 * 128 + t] = cbv;
      zq[(size_t)n4 * 128 + t] = cbv; zq[(size_t)n5 * 128 + t] = cbv;
      zq[(size_t)n6 * 128 + t] = cbv; zq[(size_t)n7 * 128 + t] = cbv;
      i += 8;
    } else {
      const int kk = sk[i];
      if (kk != kprev) {
        atomicAdd(&out6[kprev * 128 + t], 0.01f * acc);
        acc = 0.f; kprev = kk;
        cbv = cb[kk * 128 + t];
      }
      const int n = so[i];
      const float v = zq[(size_t)n * 128 + t];
      acc += v;
      const float e = cbv - v; loss = fmaf(e, e, loss);
      zq[(size_t)n * 128 + t] = cbv;
      ++i;
    }
  }
  atomicAdd(&out6[kprev * 128 + t], 0.01f * acc);
#pragma unroll
  for (int m = 32; m; m >>= 1) loss += __shfl_xor(loss, m, 64);
  if ((t & 63) == 0) red[t >> 6] = loss;
  __syncthreads();
  if (t == 0) lossp[blockIdx.x] = red[0] + red[1];
}

// ---------------- new_codebook + losses (block 511 reduces partials) -------
__global__ void k_final(const float* __restrict__ out5, const float* __restrict__ out6,
                        const float* __restrict__ ntot_p, const float* __restrict__ lossp,
                        float* __restrict__ out4, float* __restrict__ out2,
                        float* __restrict__ out3) {
  __shared__ float red[4];
  const int i = blockIdx.x * blockDim.x + threadIdx.x;
  const float ntot = *ntot_p;
  const int k = i >> 7;
  const float w = (out5[k] + 1e-5f) / (ntot + KCB * 1e-5f) * ntot;
  out4[i] = out6[i] / w;
  if (blockIdx.x == 511) {
    const int t = threadIdx.x;
    float s = 0.f;
#pragma unroll
    for (int j = 0; j < NCHUNKS / 256; ++j) s += lossp[t + 256 * j];
#pragma unroll
    for (int m = 32; m; m >>= 1) s += __shfl_xor(s, m, 64);
    if ((t & 63) == 0) red[t >> 6] = s;
    __syncthreads();
    if (t == 0) {
      const float lv = (red[0] + red[1] + red[2] + red[3]) * (1.f / 8388608.f);
      *out2 = lv; *out3 = lv;
    }
  }
}

extern "C" void kernel_launch(void* const* d_in, const int* in_sizes, int n_in,
                              void* d_out, int out_size, void* d_ws, size_t ws_size,
                              hipStream_t stream) {
  (void)in_sizes; (void)n_in; (void)out_size; (void)ws_size;
  const float* z   = (const float*)d_in[0];
  const float* cb  = (const float*)d_in[1];
  const float* emc = (const float*)d_in[2];
  const float* emw = (const float*)d_in[3];
  float* out = (float*)d_out;
  float* out0 = out;                    // quantized_st  [8388608]
  float* out1 = out + 8388608;          // idx_map (float)[65536]
  float* out2 = out + 8454144;          // commitment_loss [1]
  float* out3 = out + 8454145;          // codebook_loss   [1]
  float* out4 = out + 8454146;          // new_codebook  [131072]
  float* out5 = out + 8585218;          // new_ema_count [1024]
  float* out6 = out + 8586242;          // new_ema_weight[131072]
  float* ws = (float*)d_ws;
  uint4* cbt      = (uint4*)ws;         // [16384] uint4 = 256KB
  uint2* okbuf    = (uint2*)(ws + 65536); // [65536] uint2 = 512KB
  float* ccb      = ws + 327680;        // [1024]
  int* hist       = (int*)(ws + 328704);// [1024]
  int* cursor     = (int*)(ws + 329728);// [1024]
  float* ntot     = ws + 330752;        // [1]
  float* lossp    = ws + 331776;        // [2048] (abuts cc64 at 333824)
  double* cc64    = (double*)(ws + 333824);  // [1024] doubles (8B-aligned)
  float* z_t = out0;                    // z_t aliases out0 (overwritten in chunkreduce_q)

  hipLaunchKernelGGL(k_prep, dim3(64), dim3(256), 0, stream, cb, emw, cbt, ccb,
                     cc64, out6, hist);
  hipLaunchKernelGGL(k_argmin7, dim3(NVEC / 64), dim3(256), 0, stream,
                     z, cbt, ccb, cc64, cb, z_t, out1, hist);
  hipLaunchKernelGGL(k_scan, dim3(1), dim3(1024), 0, stream, hist, emc, cursor,
                     out5, ntot);
  hipLaunchKernelGGL(k_scatter, dim3(NVEC / 256), dim3(256), 0, stream, out1, cursor,
                     okbuf);
  hipLaunchKernelGGL(k_chunkreduce_q, dim3(NCHUNKS), dim3(128), 0, stream,
                     z_t, cb, okbuf, out6, lossp);
  hipLaunchKernelGGL(k_final, dim3(512), dim3(256), 0, stream, out5, out6, ntot,
                     lossp, out4, out2, out3);
}

// Round 19
// 126.504 us; speedup vs baseline: 1.0438x; 1.0438x over previous
//
#include <hip/hip_runtime.h>

#define NVEC 65536   // B*H*W = 64*32*32
#define KCB  1024
#define DIM  128
#define HW   1024    // H*W
#define CHUNK 32
#define NCHUNKS (NVEC / CHUNK)

typedef __bf16 b16;
typedef b16 b16x8 __attribute__((ext_vector_type(8)));
typedef float f32x16 __attribute__((ext_vector_type(16)));

static __device__ __forceinline__ unsigned short f2bf(float f) {
  unsigned int x = __float_as_uint(f);
  unsigned int r = x + 0x7fffu + ((x >> 16) & 1u);   // RNE
  return (unsigned short)(r >> 16);
}

// ---- fused prep: cbt pack + out6=0.99*emw + hist=0 + ccb/cc64 + done=0 ----
__global__ void k_prep(const float* __restrict__ cb, const float* __restrict__ emw,
                       uint4* __restrict__ cbt, float* __restrict__ ccb,
                       double* __restrict__ cc64, float* __restrict__ out6,
                       int* __restrict__ hist, int* __restrict__ done) {
  const int t = blockIdx.x * blockDim.x + threadIdx.x;   // 16384
  const int kc = t >> 11, u = t & 2047;
  const int code7 = u & 127, dch = u >> 7;
  const float* src = cb + (kc * 128 + code7) * 128 + dch * 8;
  const float4 x = *(const float4*)src;
  const float4 y = *(const float4*)(src + 4);
  uint4 o;
  o.x = (unsigned)f2bf(x.x) | ((unsigned)f2bf(x.y) << 16);
  o.y = (unsigned)f2bf(x.z) | ((unsigned)f2bf(x.w) << 16);
  o.z = (unsigned)f2bf(y.x) | ((unsigned)f2bf(y.y) << 16);
  o.w = (unsigned)f2bf(y.z) | ((unsigned)f2bf(y.w) << 16);
  cbt[t] = o;
  if (t == 0) *done = 0;
  // out6 init: out6 offset is 8B- but not 16B-aligned -> float2 stores
  const float4 e0 = *(const float4*)(emw + (size_t)t * 8);
  const float4 e1 = *(const float4*)(emw + (size_t)t * 8 + 4);
  *(float2*)(out6 + (size_t)t * 8 + 0) = make_float2(0.99f * e0.x, 0.99f * e0.y);
  *(float2*)(out6 + (size_t)t * 8 + 2) = make_float2(0.99f * e0.z, 0.99f * e0.w);
  *(float2*)(out6 + (size_t)t * 8 + 4) = make_float2(0.99f * e1.x, 0.99f * e1.y);
  *(float2*)(out6 + (size_t)t * 8 + 6) = make_float2(0.99f * e1.z, 0.99f * e1.w);
  if (t < KCB) hist[t] = 0;
  if (blockIdx.x < 4) {
    const int k = blockIdx.x * 256 + threadIdx.x;
    const float* row = cb + k * DIM;
    double s = 0.0;
#pragma unroll 8
    for (int j = 0; j < DIM; ++j) {
      const double v = (double)row[j];
      s = fma(v, v, s);
    }
    cc64[k] = s;
    ccb[k] = 512.f - 0.5f * (float)s;   // bias keeps packed scores positive
  }
}

// ---- MFMA argmin + transpose + wave-parallel f64 rescore + last-block scan
// Core kc-loop is R8/R16's structure (60us, no spill -- 7 restructure
// attempts all lost). Scan fused WITHOUT __threadfence (R14's poison: L2
// writeback per block): hist writes are device-scope atomics (coherent);
// __syncthreads() drains each wave's vmcnt before the barrier, so after one
// block-barrier ALL this block's hist atomics are complete -> done counter
// needs no fence. Last block re-reads hist via atomic loads and scans.
__global__ __launch_bounds__(256, 4) void k_argmin6(
    const float* __restrict__ z, const uint4* __restrict__ cbt,
    const float* __restrict__ ccb, const double* __restrict__ cc64,
    const float* __restrict__ cb, const float* __restrict__ emc,
    float* __restrict__ z_t, float* __restrict__ out1, int* __restrict__ hist,
    int* __restrict__ cursor, float* __restrict__ out5, float* __restrict__ ntot,
    int* __restrict__ done) {
  __shared__ __align__(16) float zs[128][65];          // 33.3 KB; Bs/hist alias
  __shared__ uint2 cand[64][2];                        // 1 KB candidate exchange
  __shared__ int isLast, wsum[4];
  __shared__ float red[4];
  uint4* Bs = (uint4*)zs;
  const int tid = threadIdx.x;
  const int l = tid & 63, wv = tid >> 6;
  const int g = l >> 5;                            // k-slice group
  const int lm = l & 31;                           // row-lane / code-lane
  const int wr = (wv & 1) * 32;                    // row group
  const int wc = wv >> 1;                          // code half (0..1)
  const int n0 = blockIdx.x * 64;
  const int b = n0 >> 10;
  const int hwbase = n0 & (HW - 1);

  // ---- phase 0: coalesced stage of the z tile into LDS
  {
    const int hw4 = (tid & 15) * 4;
    const int dr = tid >> 4;
    const float* src = z + (size_t)b * 131072 + hwbase + hw4;
#pragma unroll
    for (int j = 0; j < 8; ++j) {
      const int d = dr + 16 * j;
      const float4 v = *(const float4*)(src + d * 1024);
      zs[d][hw4 + 0] = v.x; zs[d][hw4 + 1] = v.y;
      zs[d][hw4 + 2] = v.z; zs[d][hw4 + 3] = v.w;
    }
  }
  __syncthreads();

  // ---- phase 1a: z_t rows, full-line stores (8 lanes x 16B per 512B row)
#pragma unroll
  for (int jj = 0; jj < 2; ++jj) {
    const int row = (tid >> 3) + 32 * jj;
    float* dst = z_t + ((size_t)(n0 + row)) * 128;
#pragma unroll
    for (int j = 0; j < 4; ++j) {
      const int d = (j * 8 + (tid & 7)) * 4;
      float4 v;
      v.x = zs[d + 0][row]; v.y = zs[d + 1][row];
      v.z = zs[d + 2][row]; v.w = zs[d + 3][row];
      *(float4*)(dst + d) = v;
    }
  }
  // ---- phase 1b: afrag from LDS
  uint4 afrag[8];
  {
    const int row = wr + lm;
#pragma unroll
    for (int ks = 0; ks < 8; ++ks) {
      const int d0 = ks * 16 + g * 8;
      afrag[ks].x = (unsigned)f2bf(zs[d0 + 0][row]) | ((unsigned)f2bf(zs[d0 + 1][row]) << 16);
      afrag[ks].y = (unsigned)f2bf(zs[d0 + 2][row]) | ((unsigned)f2bf(zs[d0 + 3][row]) << 16);
      afrag[ks].z = (unsigned)f2bf(zs[d0 + 4][row]) | ((unsigned)f2bf(zs[d0 + 5][row]) << 16);
      afrag[ks].w = (unsigned)f2bf(zs[d0 + 6][row]) | ((unsigned)f2bf(zs[d0 + 7][row]) << 16);
    }
  }

  unsigned pm1[16], pm2[16];
#pragma unroll
  for (int r = 0; r < 16; ++r) { pm1[r] = 0u; pm2[r] = 0u; }

  for (int kc = 0; kc < 8; ++kc) {
    __syncthreads();    // kc=0: zs readers done; kc>0: Bs readers done
#pragma unroll
    for (int i = 0; i < 8; ++i) {
      __builtin_amdgcn_global_load_lds(&cbt[kc * 2048 + wv * 512 + i * 64 + l],
                                       &Bs[wv * 512 + i * 64], 16, 0, 0);
    }
    const float cv0 = ccb[kc * 128 + (wc * 2 + 0) * 32 + lm];
    const float cv1 = ccb[kc * 128 + (wc * 2 + 1) * 32 + lm];
    __syncthreads();                               // staging landed

    f32x16 a0, a1;
#pragma unroll
    for (int j = 0; j < 16; ++j) { a0[j] = cv0; a1[j] = cv1; }
#pragma unroll
    for (int ks = 0; ks < 8; ++ks) {
      const b16x8 av = *reinterpret_cast<const b16x8*>(&afrag[ks]);
      const b16x8 bv0 = *reinterpret_cast<const b16x8*>(&Bs[(ks * 2 + g) * 128 + (wc * 2) * 32 + lm]);
      const b16x8 bv1 = *reinterpret_cast<const b16x8*>(&Bs[(ks * 2 + g) * 128 + (wc * 2 + 1) * 32 + lm]);
      a0 = __builtin_amdgcn_mfma_f32_32x32x16_bf16(av, bv0, a0, 0, 0, 0);
      a1 = __builtin_amdgcn_mfma_f32_32x32x16_bf16(av, bv1, a1, 0, 0, 0);
    }
    const unsigned ci0 = 1023u - (unsigned)(kc * 128 + (wc * 2) * 32 + lm);
    const unsigned ci1 = ci0 - 32u;
#pragma unroll
    for (int r = 0; r < 16; ++r) {
      {
        const unsigned uu = ((__float_as_uint(a0[r]) + 0x200u) & 0xFFFFFC00u) | ci0;
        const unsigned t = pm1[r] < uu ? pm1[r] : uu;
        pm1[r] = pm1[r] > uu ? pm1[r] : uu;
        pm2[r] = pm2[r] > t ? pm2[r] : t;
      }
      {
        const unsigned uu = ((__float_as_uint(a1[r]) + 0x200u) & 0xFFFFFC00u) | ci1;
        const unsigned t = pm1[r] < uu ? pm1[r] : uu;
        pm1[r] = pm1[r] > uu ? pm1[r] : uu;
        pm2[r] = pm2[r] > t ? pm2[r] : t;
      }
    }
  }

  // top-2 (max-order) merge across the 32 code-lanes -> cand LDS
#pragma unroll
  for (int r = 0; r < 16; ++r) {
    unsigned u1 = pm1[r], u2 = pm2[r];
#pragma unroll
    for (int m = 1; m < 32; m <<= 1) {
      const unsigned o1 = (unsigned)__shfl_xor((int)u1, m, 64);
      const unsigned o2 = (unsigned)__shfl_xor((int)u2, m, 64);
      const unsigned s = u1 < o1 ? u1 : o1;
      u1 = u1 > o1 ? u1 : o1;
      u2 = u2 > o2 ? u2 : o2;
      u2 = u2 > s ? u2 : s;
    }
    if (lm == 0) {
      const int lrow = wr + (r & 3) + 8 * (r >> 2) + 4 * g;
      cand[lrow][wc] = make_uint2(u1, u2);
    }
  }
  __syncthreads();                   // compute reads of Bs done; cand visible

  // ---- wave-parallel rescore: per row, cand c=l>>4 x 16 lanes (8 dims each)
  int* h = (int*)zs;                 // hist aliases dead Bs region
#pragma unroll
  for (int j = 0; j < 4; ++j) h[tid + 256 * j] = 0;
  __syncthreads();
  {
    const int db = l & 15, c = l >> 4;
#pragma unroll 2
    for (int it = 0; it < 16; ++it) {
      const int row = wv * 16 + it;
      const uint2 cd = cand[row][c >> 1];
      const unsigned u = (c & 1) ? cd.y : cd.x;
      int k = 1023 - (int)(u & 1023u);
      const int n = n0 + row;
      const float4* zr = (const float4*)(z_t + (size_t)n * DIM) + db * 2;
      const float4* cr = (const float4*)(cb + (size_t)k * DIM) + db * 2;
      const float4 z0 = zr[0], z1 = zr[1];
      const float4 c0 = cr[0], c1 = cr[1];
      double da = 0.0, dbb = 0.0;
      da = fma((double)z0.x, (double)c0.x, da);
      da = fma((double)z0.y, (double)c0.y, da);
      da = fma((double)z0.z, (double)c0.z, da);
      da = fma((double)z0.w, (double)c0.w, da);
      dbb = fma((double)z1.x, (double)c1.x, dbb);
      dbb = fma((double)z1.y, (double)c1.y, dbb);
      dbb = fma((double)z1.z, (double)c1.z, dbb);
      dbb = fma((double)z1.w, (double)c1.w, dbb);
      double s = da + dbb;
#pragma unroll
      for (int m = 1; m < 16; m <<= 1) s += __shfl_xor(s, m, 64);
      s = fma(-2.0, s, cc64[k]);
#pragma unroll
      for (int m = 16; m < 64; m <<= 1) {
        const double os = __shfl_xor(s, m, 64);
        const int ok = __shfl_xor(k, m, 64);
        if (os < s || (os == s && ok < k)) { s = os; k = ok; }
      }
      if (l == 0) {
        out1[n] = (float)k;
        atomicAdd(&h[k], 1);
      }
    }
  }
  __syncthreads();
#pragma unroll
  for (int j = 0; j < 4; ++j) {
    const int v = h[tid + 256 * j];
    if (v) atomicAdd(&hist[tid + 256 * j], v);
  }

  // ---- last-block scan (NO fence: __syncthreads drains each wave's vmcnt,
  //      hist atomics are device-scope-coherent)
  __syncthreads();                   // all 4 waves' hist atomics complete
  if (tid == 0) {
    const int old = atomicAdd(done, 1);
    isLast = (old == (int)gridDim.x - 1);
  }
  __syncthreads();
  if (isLast) {
    const int i0 = tid * 4;
    const int v0 = atomicAdd(&hist[i0 + 0], 0);
    const int v1 = atomicAdd(&hist[i0 + 1], 0);
    const int v2 = atomicAdd(&hist[i0 + 2], 0);
    const int v3 = atomicAdd(&hist[i0 + 3], 0);
    const int ts = v0 + v1 + v2 + v3;
    int x = ts;                       // wave inclusive scan of thread sums
#pragma unroll
    for (int dd = 1; dd < 64; dd <<= 1) {
      const int y = __shfl_up(x, dd, 64);
      if ((tid & 63) >= dd) x += y;
    }
    if ((tid & 63) == 63) wsum[tid >> 6] = x;
    __syncthreads();
    int wb = 0;
#pragma unroll
    for (int w = 0; w < 4; ++w) wb += (w < (tid >> 6)) ? wsum[w] : 0;
    const int base = wb + x - ts;     // exclusive prefix for this thread
    cursor[i0 + 0] = base;
    cursor[i0 + 1] = base + v0;
    cursor[i0 + 2] = base + v0 + v1;
    cursor[i0 + 3] = base + v0 + v1 + v2;
    const float o0 = 0.99f * emc[i0 + 0] + 0.01f * (float)v0;
    const float o1 = 0.99f * emc[i0 + 1] + 0.01f * (float)v1;
    const float o2 = 0.99f * emc[i0 + 2] + 0.01f * (float)v2;
    const float o3 = 0.99f * emc[i0 + 3] + 0.01f * (float)v3;
    out5[i0 + 0] = o0; out5[i0 + 1] = o1;
    out5[i0 + 2] = o2; out5[i0 + 3] = o3;
    float p = o0 + o1 + o2 + o3;
#pragma unroll
    for (int m = 32; m; m >>= 1) p += __shfl_xor(p, m, 64);
    if ((tid & 63) == 0) red[tid >> 6] = p;
    __syncthreads();
    if (tid == 0) *ntot = red[0] + red[1] + red[2] + red[3];
  }
}

// ------- scatter n's into per-code segments (packed uint2 {n,k}) -----------
__global__ void k_scatter(const float* __restrict__ idx_f, int* __restrict__ cursor,
                          uint2* __restrict__ ok) {
  const int n = blockIdx.x * blockDim.x + threadIdx.x;
  const int k = (int)idx_f[n];
  const int pos = atomicAdd(&cursor[k], 1);
  ok[pos] = make_uint2((unsigned)n, (unsigned)k);
}

// ---- chunk-parallel segmented reduce + quantized write + loss partial -----
// CHUNK=32 (grid 2048 = 8 blocks/CU): 2x TLP for the latency-bound gather.
__global__ __launch_bounds__(128) void k_chunkreduce_q(
    float* zq, const float* __restrict__ cb, const uint2* __restrict__ ok,
    float* __restrict__ out6, float* __restrict__ lossp) {
  __shared__ int so[CHUNK], sk[CHUNK];
  __shared__ float red[2];
  const int t = threadIdx.x;
  const int base = blockIdx.x * CHUNK;
  if (t < CHUNK) {
    const uint2 v = ok[base + t];
    so[t] = (int)v.x; sk[t] = (int)v.y;
  }
  __syncthreads();
  int kprev = sk[0];
  float cbv = cb[kprev * 128 + t];
  float acc = 0.f, loss = 0.f;
  int i = 0;
  while (i < CHUNK) {
    if (i + 8 <= CHUNK && sk[i] == kprev && sk[i + 7] == kprev) {
      const int n0 = so[i + 0], n1 = so[i + 1], n2 = so[i + 2], n3 = so[i + 3];
      const int n4 = so[i + 4], n5 = so[i + 5], n6 = so[i + 6], n7 = so[i + 7];
      const float v0 = zq[(size_t)n0 * 128 + t];
      const float v1 = zq[(size_t)n1 * 128 + t];
      const float v2 = zq[(size_t)n2 * 128 + t];
      const float v3 = zq[(size_t)n3 * 128 + t];
      const float v4 = zq[(size_t)n4 * 128 + t];
      const float v5 = zq[(size_t)n5 * 128 + t];
      const float v6 = zq[(size_t)n6 * 128 + t];
      const float v7 = zq[(size_t)n7 * 128 + t];
      acc += ((v0 + v1) + (v2 + v3)) + ((v4 + v5) + (v6 + v7));
      float e;
      e = cbv - v0; loss = fmaf(e, e, loss);
      e = cbv - v1; loss = fmaf(e, e, loss);
      e = cbv - v2; loss = fmaf(e, e, loss);
      e = cbv - v3; loss = fmaf(e, e, loss);
      e = cbv - v4; loss = fmaf(e, e, loss);
      e = cbv - v5; loss = fmaf(e, e, loss);
      e = cbv - v6; loss = fmaf(e, e, loss);
      e = cbv - v7; loss = fmaf(e, e, loss);
      zq[(size_t)n0 * 128 + t] = cbv; zq[(size_t)n1 * 128 + t] = cbv;
      zq[(size_t)n2 * 128 + t] = cbv; zq[(size_t)n3 * 128 + t] = cbv;
      zq[(size_t)n4 * 128 + t] = cbv; zq[(size_t)n5 * 128 + t] = cbv;
      zq[(size_t)n6 * 128 + t] = cbv; zq[(size_t)n7 * 128 + t] = cbv;
      i += 8;
    } else {
      const int kk = sk[i];
      if (kk != kprev) {
        atomicAdd(&out6[kprev * 128 + t], 0.01f * acc);
        acc = 0.f; kprev = kk;
        cbv = cb[kk * 128 + t];
      }
      const int n = so[i];
      const float v = zq[(size_t)n * 128 + t];
      acc += v;
      const float e = cbv - v; loss = fmaf(e, e, loss);
      zq[(size_t)n * 128 + t] = cbv;
      ++i;
    }
  }
  atomicAdd(&out6[kprev * 128 + t], 0.01f * acc);
#pragma unroll
  for (int m = 32; m; m >>= 1) loss += __shfl_xor(loss, m, 64);
  if ((t & 63) == 0) red[t >> 6] = loss;
  __syncthreads();
  if (t == 0) lossp[blockIdx.x] = red[0] + red[1];
}

// ---------------- new_codebook + losses (block 511 reduces partials) -------
__global__ void k_final(const float* __restrict__ out5, const float* __restrict__ out6,
                        const float* __restrict__ ntot_p, const float* __restrict__ lossp,
                        float* __restrict__ out4, float* __restrict__ out2,
                        float* __restrict__ out3) {
  __shared__ float red[4];
  const int i = blockIdx.x * blockDim.x + threadIdx.x;
  const float ntot = *ntot_p;
  const int k = i >> 7;
  const float w = (out5[k] + 1e-5f) / (ntot + KCB * 1e-5f) * ntot;
  out4[i] = out6[i] / w;
  if (blockIdx.x == 511) {
    const int t = threadIdx.x;
    float s = 0.f;
#pragma unroll
    for (int j = 0; j < NCHUNKS / 256; ++j) s += lossp[t + 256 * j];
#pragma unroll
    for (int m = 32; m; m >>= 1) s += __shfl_xor(s, m, 64);
    if ((t & 63) == 0) red[t >> 6] = s;
    __syncthreads();
    if (t == 0) {
      const float lv = (red[0] + red[1] + red[2] + red[3]) * (1.f / 8388608.f);
      *out2 = lv; *out3 = lv;
    }
  }
}

extern "C" void kernel_launch(void* const* d_in, const int* in_sizes, int n_in,
                              void* d_out, int out_size, void* d_ws, size_t ws_size,
                              hipStream_t stream) {
  (void)in_sizes; (void)n_in; (void)out_size; (void)ws_size;
  const float* z   = (const float*)d_in[0];
  const float* cb  = (const float*)d_in[1];
  const float* emc = (const float*)d_in[2];
  const float* emw = (const float*)d_in[3];
  float* out = (float*)d_out;
  float* out0 = out;                    // quantized_st  [8388608]
  float* out1 = out + 8388608;          // idx_map (float)[65536]
  float* out2 = out + 8454144;          // commitment_loss [1]
  float* out3 = out + 8454145;          // codebook_loss   [1]
  float* out4 = out + 8454146;          // new_codebook  [131072]
  float* out5 = out + 8585218;          // new_ema_count [1024]
  float* out6 = out + 8586242;          // new_ema_weight[131072]
  float* ws = (float*)d_ws;
  uint4* cbt      = (uint4*)ws;         // [16384] uint4 = 256KB
  uint2* okbuf    = (uint2*)(ws + 65536); // [65536] uint2 = 512KB
  float* ccb      = ws + 327680;        // [1024]
  int* hist       = (int*)(ws + 328704);// [1024]
  int* cursor     = (int*)(ws + 329728);// [1024]
  float* ntot     = ws + 330752;        // [1]
  int* done       = (int*)(ws + 330756);// [1]
  float* lossp    = ws + 331776;        // [2048] (abuts cc64 at 333824)
  double* cc64    = (double*)(ws + 333824);  // [1024] doubles (8B-aligned)
  float* z_t = out0;                    // z_t aliases out0 (overwritten in chunkreduce_q)

  hipLaunchKernelGGL(k_prep, dim3(64), dim3(256), 0, stream, cb, emw, cbt, ccb,
                     cc64, out6, hist, done);
  hipLaunchKernelGGL(k_argmin6, dim3(NVEC / 64), dim3(256), 0, stream,
                     z, cbt, ccb, cc64, cb, emc, z_t, out1, hist, cursor,
                     out5, ntot, done);
  hipLaunchKernelGGL(k_scatter, dim3(NVEC / 256), dim3(256), 0, stream, out1, cursor,
                     okbuf);
  hipLaunchKernelGGL(k_chunkreduce_q, dim3(NCHUNKS), dim3(128), 0, stream,
                     z_t, cb, okbuf, out6, lossp);
  hipLaunchKernelGGL(k_final, dim3(512), dim3(256), 0, stream, out5, out6, ntot,
                     lossp, out4, out2, out3);
}

// Round 20
// 124.236 us; speedup vs baseline: 1.0628x; 1.0183x over previous
//
#include <hip/hip_runtime.h>

#define NVEC 65536   // B*H*W = 64*32*32
#define KCB  1024
#define DIM  128
#define HW   1024    // H*W
#define CHUNK 32
#define NCHUNKS (NVEC / CHUNK)

typedef __bf16 b16;
typedef b16 b16x8 __attribute__((ext_vector_type(8)));
typedef float f32x16 __attribute__((ext_vector_type(16)));

static __device__ __forceinline__ unsigned short f2bf(float f) {
  unsigned int x = __float_as_uint(f);
  unsigned int r = x + 0x7fffu + ((x >> 16) & 1u);   // RNE
  return (unsigned short)(r >> 16);
}

// ---- fused prep: cbt pack + out6=0.99*emw + hist=0 + ccb/cc64 + done=0 ----
__global__ void k_prep(const float* __restrict__ cb, const float* __restrict__ emw,
                       uint4* __restrict__ cbt, float* __restrict__ ccb,
                       double* __restrict__ cc64, float* __restrict__ out6,
                       int* __restrict__ hist, int* __restrict__ done) {
  const int t = blockIdx.x * blockDim.x + threadIdx.x;   // 16384
  const int kc = t >> 11, u = t & 2047;
  const int code7 = u & 127, dch = u >> 7;
  const float* src = cb + (kc * 128 + code7) * 128 + dch * 8;
  const float4 x = *(const float4*)src;
  const float4 y = *(const float4*)(src + 4);
  uint4 o;
  o.x = (unsigned)f2bf(x.x) | ((unsigned)f2bf(x.y) << 16);
  o.y = (unsigned)f2bf(x.z) | ((unsigned)f2bf(x.w) << 16);
  o.z = (unsigned)f2bf(y.x) | ((unsigned)f2bf(y.y) << 16);
  o.w = (unsigned)f2bf(y.z) | ((unsigned)f2bf(y.w) << 16);
  cbt[t] = o;
  if (t == 0) *done = 0;
  // out6 init: out6 offset is 8B- but not 16B-aligned -> float2 stores
  const float4 e0 = *(const float4*)(emw + (size_t)t * 8);
  const float4 e1 = *(const float4*)(emw + (size_t)t * 8 + 4);
  *(float2*)(out6 + (size_t)t * 8 + 0) = make_float2(0.99f * e0.x, 0.99f * e0.y);
  *(float2*)(out6 + (size_t)t * 8 + 2) = make_float2(0.99f * e0.z, 0.99f * e0.w);
  *(float2*)(out6 + (size_t)t * 8 + 4) = make_float2(0.99f * e1.x, 0.99f * e1.y);
  *(float2*)(out6 + (size_t)t * 8 + 6) = make_float2(0.99f * e1.z, 0.99f * e1.w);
  if (t < KCB) hist[t] = 0;
  if (blockIdx.x < 4) {
    const int k = blockIdx.x * 256 + threadIdx.x;
    const float* row = cb + k * DIM;
    double s = 0.0;
#pragma unroll 8
    for (int j = 0; j < DIM; ++j) {
      const double v = (double)row[j];
      s = fma(v, v, s);
    }
    cc64[k] = s;
    ccb[k] = 512.f - 0.5f * (float)s;   // bias keeps packed scores positive
  }
}

// ---- MFMA argmin v8: 8-wave 128-row blocks, true double-buffered chunks ---
// 2 blocks/CU (= same 16 waves/CU as R8's 4x4). LDS ~67KB: zs[128][129]
// reused as BsA/BsB (2 x 32KB = one full 128-code chunk each). Per chunk:
// barrier (drains stage(c); readers of nxt done) -> issue stage(c+1)->nxt ->
// compute(c, cur). 8 barriers total (R8: 16), staging hidden under a FULL
// compute body (R17's half-size chunks lost). Per-wave register profile is
// bit-identical to R8's proven 64-VGPR core: afrag 8xuint4, a0/a1, scalar
// ccb loads, no runtime-indexed arrays. Wave wv: rows (wv&3)*32, code half
// ch=wv>>2 -- same code partition as R16 -> identical candidates/indices.
// Tail: wave-parallel f64 rescore + fence-free last-block scan (R18).
__global__ __launch_bounds__(512, 4) void k_argmin8(
    const float* __restrict__ z, const uint4* __restrict__ cbt,
    const float* __restrict__ ccb, const double* __restrict__ cc64,
    const float* __restrict__ cb, const float* __restrict__ emc,
    float* __restrict__ z_t, float* __restrict__ out1, int* __restrict__ hist,
    int* __restrict__ cursor, float* __restrict__ out5, float* __restrict__ ntot,
    int* __restrict__ done) {
  __shared__ __align__(16) float zs[128][129];         // 66 KB; BsA/BsB/hist alias
  __shared__ uint2 cand[128][2];                       // 2 KB candidate exchange
  __shared__ int isLast, wsum[8];
  __shared__ float red[8];
  uint4* BsA = (uint4*)zs;                             // 32 KB (2048 uint4)
  uint4* BsB = ((uint4*)zs) + 2048;                    // 32 KB
  const int tid = threadIdx.x;
  const int l = tid & 63, wv = tid >> 6;           // 8 waves
  const int g = l >> 5;                            // k-slice group
  const int lm = l & 31;                           // row-lane / code-lane
  const int wr = (wv & 3) * 32;                    // row group (4 x 32)
  const int ch = wv >> 2;                          // code half (0..1)
  const int n0 = blockIdx.x * 128;
  const int b = n0 >> 10;
  const int hwbase = n0 & (HW - 1);

  // ---- phase 0: coalesced stage of the z tile [128 d][128 hw] into LDS
  {
    const int hw4 = (tid & 31) * 4;
    const int dr = tid >> 5;                       // 0..15
    const float* src = z + (size_t)b * 131072 + hwbase + hw4;
#pragma unroll
    for (int j = 0; j < 8; ++j) {
      const int d = dr + 16 * j;
      const float4 v = *(const float4*)(src + d * 1024);
      zs[d][hw4 + 0] = v.x; zs[d][hw4 + 1] = v.y;
      zs[d][hw4 + 2] = v.z; zs[d][hw4 + 3] = v.w;
    }
  }
  __syncthreads();

  // ---- phase 1a: z_t rows, full-line stores (8 lanes x 16B per 512B row)
#pragma unroll
  for (int jj = 0; jj < 2; ++jj) {
    const int row = (tid >> 3) + 64 * jj;          // 0..127
    float* dst = z_t + ((size_t)(n0 + row)) * 128;
#pragma unroll
    for (int j = 0; j < 4; ++j) {
      const int d = (j * 8 + (tid & 7)) * 4;
      float4 v;
      v.x = zs[d + 0][row]; v.y = zs[d + 1][row];
      v.z = zs[d + 2][row]; v.w = zs[d + 3][row];
      *(float4*)(dst + d) = v;
    }
  }
  // ---- phase 1b: afrag from LDS (this wave's 32 rows)
  uint4 afrag[8];
  {
    const int row = wr + lm;
#pragma unroll
    for (int ks = 0; ks < 8; ++ks) {
      const int d0 = ks * 16 + g * 8;
      afrag[ks].x = (unsigned)f2bf(zs[d0 + 0][row]) | ((unsigned)f2bf(zs[d0 + 1][row]) << 16);
      afrag[ks].y = (unsigned)f2bf(zs[d0 + 2][row]) | ((unsigned)f2bf(zs[d0 + 3][row]) << 16);
      afrag[ks].z = (unsigned)f2bf(zs[d0 + 4][row]) | ((unsigned)f2bf(zs[d0 + 5][row]) << 16);
      afrag[ks].w = (unsigned)f2bf(zs[d0 + 6][row]) | ((unsigned)f2bf(zs[d0 + 7][row]) << 16);
    }
  }

  unsigned pm1[16], pm2[16];
#pragma unroll
  for (int r = 0; r < 16; ++r) { pm1[r] = 0u; pm2[r] = 0u; }

  __syncthreads();                     // all zs reads done; Bs may overwrite
  // prologue: stage chunk 0 into BsA (each wave stages 256 contiguous uint4)
#pragma unroll
  for (int i = 0; i < 4; ++i) {
    __builtin_amdgcn_global_load_lds(&cbt[wv * 256 + i * 64 + l],
                                     &BsA[wv * 256 + i * 64], 16, 0, 0);
  }

  for (int c = 0; c < 8; ++c) {
    __syncthreads();                   // drains stage(c); readers of nxt done
    const uint4* cur = (c & 1) ? BsB : BsA;
    uint4* nxt = (c & 1) ? BsA : BsB;
    if (c < 7) {                       // issue stage(c+1): lands under compute
#pragma unroll
      for (int i = 0; i < 4; ++i) {
        __builtin_amdgcn_global_load_lds(&cbt[(c + 1) * 2048 + wv * 256 + i * 64 + l],
                                         &nxt[wv * 256 + i * 64], 16, 0, 0);
      }
    }
    const float cv0 = ccb[c * 128 + (ch * 2 + 0) * 32 + lm];
    const float cv1 = ccb[c * 128 + (ch * 2 + 1) * 32 + lm];
    f32x16 a0, a1;
#pragma unroll
    for (int j = 0; j < 16; ++j) { a0[j] = cv0; a1[j] = cv1; }
#pragma unroll
    for (int ks = 0; ks < 8; ++ks) {
      const b16x8 av = *reinterpret_cast<const b16x8*>(&afrag[ks]);
      const b16x8 bv0 = *reinterpret_cast<const b16x8*>(&cur[(ks * 2 + g) * 128 + (ch * 2) * 32 + lm]);
      const b16x8 bv1 = *reinterpret_cast<const b16x8*>(&cur[(ks * 2 + g) * 128 + (ch * 2 + 1) * 32 + lm]);
      a0 = __builtin_amdgcn_mfma_f32_32x32x16_bf16(av, bv0, a0, 0, 0, 0);
      a1 = __builtin_amdgcn_mfma_f32_32x32x16_bf16(av, bv1, a1, 0, 0, 0);
    }
    const unsigned ci0 = 1023u - (unsigned)(c * 128 + (ch * 2) * 32 + lm);
    const unsigned ci1 = ci0 - 32u;
#pragma unroll
    for (int r = 0; r < 16; ++r) {
      {
        const unsigned uu = ((__float_as_uint(a0[r]) + 0x200u) & 0xFFFFFC00u) | ci0;
        const unsigned t = pm1[r] < uu ? pm1[r] : uu;
        pm1[r] = pm1[r] > uu ? pm1[r] : uu;
        pm2[r] = pm2[r] > t ? pm2[r] : t;
      }
      {
        const unsigned uu = ((__float_as_uint(a1[r]) + 0x200u) & 0xFFFFFC00u) | ci1;
        const unsigned t = pm1[r] < uu ? pm1[r] : uu;
        pm1[r] = pm1[r] > uu ? pm1[r] : uu;
        pm2[r] = pm2[r] > t ? pm2[r] : t;
      }
    }
  }

  // top-2 (max-order) merge across the 32 code-lanes -> cand LDS
#pragma unroll
  for (int r = 0; r < 16; ++r) {
    unsigned u1 = pm1[r], u2 = pm2[r];
#pragma unroll
    for (int m = 1; m < 32; m <<= 1) {
      const unsigned o1 = (unsigned)__shfl_xor((int)u1, m, 64);
      const unsigned o2 = (unsigned)__shfl_xor((int)u2, m, 64);
      const unsigned s = u1 < o1 ? u1 : o1;
      u1 = u1 > o1 ? u1 : o1;
      u2 = u2 > o2 ? u2 : o2;
      u2 = u2 > s ? u2 : s;
    }
    if (lm == 0) {
      const int lrow = wr + (r & 3) + 8 * (r >> 2) + 4 * g;
      cand[lrow][ch] = make_uint2(u1, u2);
    }
  }
  __syncthreads();                   // compute reads of Bs done; cand visible

  // ---- wave-parallel rescore: per row, cand c=l>>4 x 16 lanes (8 dims each)
  int* h = (int*)zs;                 // hist aliases dead Bs region
#pragma unroll
  for (int j = 0; j < 2; ++j) h[tid + 512 * j] = 0;
  __syncthreads();
  {
    const int db = l & 15, c = l >> 4;
#pragma unroll 2
    for (int it = 0; it < 16; ++it) {
      const int row = wv * 16 + it;  // 0..127
      const uint2 cd = cand[row][c >> 1];
      const unsigned u = (c & 1) ? cd.y : cd.x;
      int k = 1023 - (int)(u & 1023u);
      const int n = n0 + row;
      const float4* zr = (const float4*)(z_t + (size_t)n * DIM) + db * 2;
      const float4* cr = (const float4*)(cb + (size_t)k * DIM) + db * 2;
      const float4 z0 = zr[0], z1 = zr[1];
      const float4 c0 = cr[0], c1 = cr[1];
      double da = 0.0, dbb = 0.0;
      da = fma((double)z0.x, (double)c0.x, da);
      da = fma((double)z0.y, (double)c0.y, da);
      da = fma((double)z0.z, (double)c0.z, da);
      da = fma((double)z0.w, (double)c0.w, da);
      dbb = fma((double)z1.x, (double)c1.x, dbb);
      dbb = fma((double)z1.y, (double)c1.y, dbb);
      dbb = fma((double)z1.z, (double)c1.z, dbb);
      dbb = fma((double)z1.w, (double)c1.w, dbb);
      double s = da + dbb;
#pragma unroll
      for (int m = 1; m < 16; m <<= 1) s += __shfl_xor(s, m, 64);
      s = fma(-2.0, s, cc64[k]);
#pragma unroll
      for (int m = 16; m < 64; m <<= 1) {
        const double os = __shfl_xor(s, m, 64);
        const int ok = __shfl_xor(k, m, 64);
        if (os < s || (os == s && ok < k)) { s = os; k = ok; }
      }
      if (l == 0) {
        out1[n] = (float)k;
        atomicAdd(&h[k], 1);
      }
    }
  }
  __syncthreads();
#pragma unroll
  for (int j = 0; j < 2; ++j) {
    const int v = h[tid + 512 * j];
    if (v) atomicAdd(&hist[tid + 512 * j], v);
  }

  // ---- last-block scan (fence-free: barrier drains vmcnt; atomics coherent)
  __syncthreads();                   // all waves' hist atomics complete
  if (tid == 0) {
    const int old = atomicAdd(done, 1);
    isLast = (old == (int)gridDim.x - 1);
  }
  __syncthreads();
  if (isLast) {
    const int i0 = tid * 2;
    const int v0 = atomicAdd(&hist[i0 + 0], 0);
    const int v1 = atomicAdd(&hist[i0 + 1], 0);
    const int ts = v0 + v1;
    int x = ts;                       // wave inclusive scan of thread sums
#pragma unroll
    for (int dd = 1; dd < 64; dd <<= 1) {
      const int y = __shfl_up(x, dd, 64);
      if ((tid & 63) >= dd) x += y;
    }
    if ((tid & 63) == 63) wsum[tid >> 6] = x;
    __syncthreads();
    int wb = 0;
#pragma unroll
    for (int w = 0; w < 8; ++w) wb += (w < (tid >> 6)) ? wsum[w] : 0;
    const int base = wb + x - ts;     // exclusive prefix for this thread
    cursor[i0 + 0] = base;
    cursor[i0 + 1] = base + v0;
    const float o0 = 0.99f * emc[i0 + 0] + 0.01f * (float)v0;
    const float o1 = 0.99f * emc[i0 + 1] + 0.01f * (float)v1;
    out5[i0 + 0] = o0; out5[i0 + 1] = o1;
    float p = o0 + o1;
#pragma unroll
    for (int m = 32; m; m >>= 1) p += __shfl_xor(p, m, 64);
    if ((tid & 63) == 0) red[tid >> 6] = p;
    __syncthreads();
    if (tid == 0) {
      float s = 0.f;
#pragma unroll
      for (int w = 0; w < 8; ++w) s += red[w];
      *ntot = s;
    }
  }
}

// ------- scatter n's into per-code segments (packed uint2 {n,k}) -----------
__global__ void k_scatter(const float* __restrict__ idx_f, int* __restrict__ cursor,
                          uint2* __restrict__ ok) {
  const int n = blockIdx.x * blockDim.x + threadIdx.x;
  const int k = (int)idx_f[n];
  const int pos = atomicAdd(&cursor[k], 1);
  ok[pos] = make_uint2((unsigned)n, (unsigned)k);
}

// ---- chunk-parallel segmented reduce + quantized write + loss partial -----
// CHUNK=32 (grid 2048 = 8 blocks/CU): 2x TLP for the latency-bound gather.
__global__ __launch_bounds__(128) void k_chunkreduce_q(
    float* zq, const float* __restrict__ cb, const uint2* __restrict__ ok,
    float* __restrict__ out6, float* __restrict__ lossp) {
  __shared__ int so[CHUNK], sk[CHUNK];
  __shared__ float red[2];
  const int t = threadIdx.x;
  const int base = blockIdx.x * CHUNK;
  if (t < CHUNK) {
    const uint2 v = ok[base + t];
    so[t] = (int)v.x; sk[t] = (int)v.y;
  }
  __syncthreads();
  int kprev = sk[0];
  float cbv = cb[kprev * 128 + t];
  float acc = 0.f, loss = 0.f;
  int i = 0;
  while (i < CHUNK) {
    if (i + 8 <= CHUNK && sk[i] == kprev && sk[i + 7] == kprev) {
      const int n0 = so[i + 0], n1 = so[i + 1], n2 = so[i + 2], n3 = so[i + 3];
      const int n4 = so[i + 4], n5 = so[i + 5], n6 = so[i + 6], n7 = so[i + 7];
      const float v0 = zq[(size_t)n0 * 128 + t];
      const float v1 = zq[(size_t)n1 * 128 + t];
      const float v2 = zq[(size_t)n2 * 128 + t];
      const float v3 = zq[(size_t)n3 * 128 + t];
      const float v4 = zq[(size_t)n4 * 128 + t];
      const float v5 = zq[(size_t)n5 * 128 + t];
      const float v6 = zq[(size_t)n6 * 128 + t];
      const float v7 = zq[(size_t)n7 * 128 + t];
      acc += ((v0 + v1) + (v2 + v3)) + ((v4 + v5) + (v6 + v7));
      float e;
      e = cbv - v0; loss = fmaf(e, e, loss);
      e = cbv - v1; loss = fmaf(e, e, loss);
      e = cbv - v2; loss = fmaf(e, e, loss);
      e = cbv - v3; loss = fmaf(e, e, loss);
      e = cbv - v4; loss = fmaf(e, e, loss);
      e = cbv - v5; loss = fmaf(e, e, loss);
      e = cbv - v6; loss = fmaf(e, e, loss);
      e = cbv - v7; loss = fmaf(e, e, loss);
      zq[(size_t)n0 * 128 + t] = cbv; zq[(size_t)n1 * 128 + t] = cbv;
      zq[(size_t)n2 * 128 + t] = cbv; zq[(size_t)n3 * 128 + t] = cbv;
      zq[(size_t)n4 * 128 + t] = cbv; zq[(size_t)n5 * 128 + t] = cbv;
      zq[(size_t)n6 * 128 + t] = cbv; zq[(size_t)n7 * 128 + t] = cbv;
      i += 8;
    } else {
      const int kk = sk[i];
      if (kk != kprev) {
        atomicAdd(&out6[kprev * 128 + t], 0.01f * acc);
        acc = 0.f; kprev = kk;
        cbv = cb[kk * 128 + t];
      }
      const int n = so[i];
      const float v = zq[(size_t)n * 128 + t];
      acc += v;
      const float e = cbv - v; loss = fmaf(e, e, loss);
      zq[(size_t)n * 128 + t] = cbv;
      ++i;
    }
  }
  atomicAdd(&out6[kprev * 128 + t], 0.01f * acc);
#pragma unroll
  for (int m = 32; m; m >>= 1) loss += __shfl_xor(loss, m, 64);
  if ((t & 63) == 0) red[t >> 6] = loss;
  __syncthreads();
  if (t == 0) lossp[blockIdx.x] = red[0] + red[1];
}

// ---------------- new_codebook + losses (block 511 reduces partials) -------
__global__ void k_final(const float* __restrict__ out5, const float* __restrict__ out6,
                        const float* __restrict__ ntot_p, const float* __restrict__ lossp,
                        float* __restrict__ out4, float* __restrict__ out2,
                        float* __restrict__ out3) {
  __shared__ float red[4];
  const int i = blockIdx.x * blockDim.x + threadIdx.x;
  const float ntot = *ntot_p;
  const int k = i >> 7;
  const float w = (out5[k] + 1e-5f) / (ntot + KCB * 1e-5f) * ntot;
  out4[i] = out6[i] / w;
  if (blockIdx.x == 511) {
    const int t = threadIdx.x;
    float s = 0.f;
#pragma unroll
    for (int j = 0; j < NCHUNKS / 256; ++j) s += lossp[t + 256 * j];
#pragma unroll
    for (int m = 32; m; m >>= 1) s += __shfl_xor(s, m, 64);
    if ((t & 63) == 0) red[t >> 6] = s;
    __syncthreads();
    if (t == 0) {
      const float lv = (red[0] + red[1] + red[2] + red[3]) * (1.f / 8388608.f);
      *out2 = lv; *out3 = lv;
    }
  }
}

extern "C" void kernel_launch(void* const* d_in, const int* in_sizes, int n_in,
                              void* d_out, int out_size, void* d_ws, size_t ws_size,
                              hipStream_t stream) {
  (void)in_sizes; (void)n_in; (void)out_size; (void)ws_size;
  const float* z   = (const float*)d_in[0];
  const float* cb  = (const float*)d_in[1];
  const float* emc = (const float*)d_in[2];
  const float* emw = (const float*)d_in[3];
  float* out = (float*)d_out;
  float* out0 = out;                    // quantized_st  [8388608]
  float* out1 = out + 8388608;          // idx_map (float)[65536]
  float* out2 = out + 8454144;          // commitment_loss [1]
  float* out3 = out + 8454145;          // codebook_loss   [1]
  float* out4 = out + 8454146;          // new_codebook  [131072]
  float* out5 = out + 8585218;          // new_ema_count [1024]
  float* out6 = out + 8586242;          // new_ema_weight[131072]
  float* ws = (float*)d_ws;
  uint4* cbt      = (uint4*)ws;         // [16384] uint4 = 256KB
  uint2* okbuf    = (uint2*)(ws + 65536); // [65536] uint2 = 512KB
  float* ccb      = ws + 327680;        // [1024]
  int* hist       = (int*)(ws + 328704);// [1024]
  int* cursor     = (int*)(ws + 329728);// [1024]
  float* ntot     = ws + 330752;        // [1]
  int* done       = (int*)(ws + 330756);// [1]
  float* lossp    = ws + 331776;        // [2048] (abuts cc64 at 333824)
  double* cc64    = (double*)(ws + 333824);  // [1024] doubles (8B-aligned)
  float* z_t = out0;                    // z_t aliases out0 (overwritten in chunkreduce_q)

  hipLaunchKernelGGL(k_prep, dim3(64), dim3(256), 0, stream, cb, emw, cbt, ccb,
                     cc64, out6, hist, done);
  hipLaunchKernelGGL(k_argmin8, dim3(NVEC / 128), dim3(512), 0, stream,
                     z, cbt, ccb, cc64, cb, emc, z_t, out1, hist, cursor,
                     out5, ntot, done);
  hipLaunchKernelGGL(k_scatter, dim3(NVEC / 256), dim3(256), 0, stream, out1, cursor,
                     okbuf);
  hipLaunchKernelGGL(k_chunkreduce_q, dim3(NCHUNKS), dim3(128), 0, stream,
                     z_t, cb, okbuf, out6, lossp);
  hipLaunchKernelGGL(k_final, dim3(512), dim3(256), 0, stream, out5, out6, ntot,
                     lossp, out4, out2, out3);
}